// Round 5
// baseline (197.849 us; speedup 1.0000x reference)
//
#include <hip/hip_runtime.h>

// Problem constants
#define MD 4
#define PATCH 9          // 2*MD+1
#define NBAND 256        // band-compute blocks: (b, ty) = 4 * 64
#define NZERO 4096       // zero-streaming blocks
// feat1/feat2: (4, 256, 64, 64) fp32
// out: (4, 4096, 64, 64) fp32 = 256 MB
//
// out[b, ty*64+tx, y, x] = sum_c f1[b,c,y,x] * f2[b,c,ty,tx]  if |ty-y|<=4 && |tx-x|<=4, else 0.
//
// Row partition: zero blocks write rows |y-ty|>4 (~220 MB); band blocks write |y-ty|<=4 (~36 MB).
// Band: f2[b,:,ty,:] staged in LDS (4 rounds x 64 channels x 16KB); compute reads the shifted
// f2 window via ds_read (NOT shuffle-of-fresh-load) -> no serial HBM round-trip per channel.
// LDS union: f2 round tile (16 KB) and sVals (20.7 KB) share one buffer (disjoint lifetimes).

__global__ __launch_bounds__(256, 4) void cv_kernel(
    const float* __restrict__ f1,
    const float* __restrict__ f2,
    float* __restrict__ out)
{
    const int tid = threadIdx.x;

    __shared__ float uLds[64 * 81];   // 20736 B: f2 tile [64][64] during compute, sVals[64][81] after

    // ---------------- zero-streaming blocks ----------------
    if (blockIdx.x >= NBAND) {
        // float4 index i: bits [0:4)=x4, [4:10)=y, [10:16)=tx, [16:22)=ty, [22:24)=b
        float4* o4 = (float4*)out;
        const float4 z4 = make_float4(0.f, 0.f, 0.f, 0.f);
        const int total4 = 4 * 4096 * 64 * 16;            // 16,777,216
        const int stride = NZERO * 256;
        for (int i = (blockIdx.x - NBAND) * 256 + tid; i < total4; i += stride) {
            int y  = (i >> 4) & 63;
            int ty = (i >> 16) & 63;
            int dy = y - ty;
            if (dy < -MD || dy > MD)
                o4[i] = z4;
        }
        return;
    }

    // ---------------- band-compute blocks ----------------
    const int bty = blockIdx.x;       // 0..255
    const int b   = bty >> 6;         // 0..3
    const int ty  = bty & 63;         // 0..63
    const int lane = tid & 63;        // u = x position
    const int wq   = tid >> 6;        // wave id -> dyi subset

    // Wave wq owns dyi rows {0,1}/{2,3}/{4,5}/{6,7,8}. All waves compute a uniform
    // 3-row shape; waves 0..2's third row duplicates the next wave's first and is discarded.
    const int dy0 = wq * 2;
    const int nd  = (wq == 3) ? 3 : 2;

    float acc[3][PATCH];
#pragma unroll
    for (int i = 0; i < 3; ++i)
#pragma unroll
        for (int j = 0; j < PATCH; ++j) acc[i][j] = 0.f;

    int yoff[3];                      // clamped f1 row offsets (floats); invalid rows discarded
#pragma unroll
    for (int i = 0; i < 3; ++i) {
        int y = ty + dy0 + i - MD;
        y = y < 0 ? 0 : (y > 63 ? 63 : y);
        yoff[i] = y * 64;
    }

    const float*  f1p = f1 + (size_t)(b * 256) * 4096 + lane;
    const float4* f2g = (const float4*)f2 + (size_t)(b * 256) * 1024 + ty * 16; // + c*1024 + x4
    float4* uF4 = (float4*)uLds;

    for (int q = 0; q < 4; ++q) {
        __syncthreads();              // previous round's LDS reads complete before overwrite
        // stage f2[b, q*64+cl, ty, :] -> uLds[cl*64 + x]   (1024 float4, 4 per thread)
#pragma unroll
        for (int k = 0; k < 4; ++k) {
            int j  = k * 256 + tid;   // 0..1023
            int cl = j >> 4, x4 = j & 15;
            uF4[j] = f2g[(size_t)(q * 64 + cl) * 1024 + x4];
        }
        __syncthreads();

        const float* f1q = f1p + (size_t)q * 64 * 4096;
#pragma unroll 4
        for (int cl = 0; cl < 64; ++cl) {
            const float* f1c = f1q + (size_t)cl * 4096;
            float f1v[3];
#pragma unroll
            for (int i = 0; i < 3; ++i)
                f1v[i] = f1c[yoff[i]];                     // batched coalesced loads
            const float* row = uLds + cl * 64;
            float sh[PATCH];
#pragma unroll
            for (int dxi = 0; dxi < PATCH; ++dxi) {
                int xx = lane - dxi + MD;                  // == tx; clamp, invalid discarded later
                xx = xx < 0 ? 0 : (xx > 63 ? 63 : xx);
                sh[dxi] = row[xx];                         // ds_read, 2-way alias = free
            }
#pragma unroll
            for (int i = 0; i < 3; ++i)
#pragma unroll
                for (int dxi = 0; dxi < PATCH; ++dxi)
                    acc[i][dxi] = fmaf(f1v[i], sh[dxi], acc[i][dxi]);
        }
    }
    __syncthreads();                  // all f2-tile reads done; uLds becomes sVals

    // sVals[tx][dyi*9+dxi] = val(tx, y=ty+dyi-4, x=tx+dxi-4); exclusive writers per entry.
    float (*sVals)[81] = (float(*)[81])uLds;
#pragma unroll
    for (int i = 0; i < 3; ++i) {
        if (i >= nd) continue;        // wave-uniform
        int dyi = dy0 + i;
        int y = ty + dyi - MD;
        if ((unsigned)y >= 64u) continue;
#pragma unroll
        for (int dxi = 0; dxi < PATCH; ++dxi) {
            int tx = lane - (dxi - MD);
            if ((unsigned)tx < 64u)
                sVals[tx][dyi * PATCH + dxi] = acc[i][dxi];  // stride 81: conflict-free
        }
    }

    __syncthreads();

    // Band rows: full 64-float rows (9-wide value window, zeros elsewhere).
    float4* out4 = (float4*)(out + (size_t)(b * 4096 + ty * 64) * 4096);
    const int q4  = tid & 15;         // float4 index within a row
    const int ro  = tid >> 4;         // row offset 0..15
    for (int rb = 0; rb < 64 * PATCH; rb += 16) {
        int row = rb + ro;            // row = tx*9 + dyi
        int tx  = row / PATCH;        // const divisor -> magic multiply
        int dyi = row - tx * PATCH;
        int y   = ty + dyi - MD;
        if ((unsigned)y < 64u) {
            float comp[4];
#pragma unroll
            for (int j = 0; j < 4; ++j) {
                int x  = q4 * 4 + j;
                int dx = x - tx;
                comp[j] = (dx >= -MD && dx <= MD) ? sVals[tx][dyi * PATCH + dx + MD] : 0.f;
            }
            out4[tx * 1024 + y * 16 + q4] = make_float4(comp[0], comp[1], comp[2], comp[3]);
        }
    }
}

extern "C" void kernel_launch(void* const* d_in, const int* in_sizes, int n_in,
                              void* d_out, int out_size, void* d_ws, size_t ws_size,
                              hipStream_t stream) {
    const float* f1 = (const float*)d_in[0];
    const float* f2 = (const float*)d_in[1];
    float* out = (float*)d_out;
    cv_kernel<<<NBAND + NZERO, 256, 0, stream>>>(f1, f2, out);
}

// Round 6
// 109.964 us; speedup vs baseline: 1.7992x; 1.7992x over previous
//
#include <hip/hip_runtime.h>

// Problem constants
#define MD 4
#define PATCH 9          // 2*MD+1
#define NBAND 256        // band-compute blocks: (b, ty) = 4 * 64
#define NZERO 1024       // zero-streaming blocks
#define BT 1024          // threads per block (16 waves)
// feat1/feat2: (4, 256, 64, 64) fp32
// out: (4, 4096, 64, 64) fp32 = 256 MB
//
// out[b, ty*64+tx, y, x] = sum_c f1[b,c,y,x] * f2[b,c,ty,tx]  if |ty-y|<=4 && |tx-x|<=4, else 0.
//
// Row partition: zero blocks write rows |y-ty|>4 (~220 MB); band blocks write |y-ty|<=4 (~36 MB).
// Band block = 1024 threads, 16 waves = (cq, dyg): cq = channel quarter (64 ch), dyg = dy rows
// {0,1}/{2,3}/{4,5}/{6,7,8}. <=27 acc/thread (no spill), 4 waves/SIMD for latency hiding.
// Channel partials merged via LDS atomicAdd.

template<int ND>
__device__ __forceinline__ void band_work(
    const float* __restrict__ f1base,   // f1 + (b*256+cq*64)*4096 + lane
    const float* __restrict__ f2base,   // f2 + (b*256+cq*64)*4096 + ty*64 + lane
    int ty, int dy0, int lane,
    float (*sVals)[81])
{
    float acc[ND][PATCH];
#pragma unroll
    for (int i = 0; i < ND; ++i)
#pragma unroll
        for (int j = 0; j < PATCH; ++j) acc[i][j] = 0.f;

    int yoff[ND];                        // clamped row offsets; invalid rows discarded at merge
#pragma unroll
    for (int i = 0; i < ND; ++i) {
        int y = ty + dy0 + i - MD;
        y = y < 0 ? 0 : (y > 63 ? 63 : y);
        yoff[i] = y * 64;
    }

#pragma unroll 4
    for (int c = 0; c < 64; ++c) {
        const float* f1c = f1base + (size_t)c * 4096;
        float f2v = f2base[(size_t)c * 4096];         // f2[c, ty, lane]
        float f1v[ND];
#pragma unroll
        for (int i = 0; i < ND; ++i)
            f1v[i] = f1c[yoff[i]];                    // batched coalesced loads
        float sh[PATCH];
#pragma unroll
        for (int dxi = 0; dxi < PATCH; ++dxi)
            sh[dxi] = __shfl(f2v, lane - (dxi - MD), 64);   // f2[c, ty, u-dx]
#pragma unroll
        for (int i = 0; i < ND; ++i)
#pragma unroll
            for (int dxi = 0; dxi < PATCH; ++dxi)
                acc[i][dxi] = fmaf(f1v[i], sh[dxi], acc[i][dxi]);
    }

    // Merge channel partials: entry (tx,dyi,dxi) owned by lane tx+dxi-4 of the 4 cq-waves.
#pragma unroll
    for (int i = 0; i < ND; ++i) {
        int dyi = dy0 + i;
        int y = ty + dyi - MD;
        if ((unsigned)y >= 64u) continue;             // uniform per wave
#pragma unroll
        for (int dxi = 0; dxi < PATCH; ++dxi) {
            int tx = lane - (dxi - MD);
            if ((unsigned)tx < 64u)
                atomicAdd(&sVals[tx][dyi * PATCH + dxi], acc[i][dxi]);  // stride 81: conflict-free
        }
    }
}

__global__ __launch_bounds__(BT, 4) void cv_kernel(
    const float* __restrict__ f1,
    const float* __restrict__ f2,
    float* __restrict__ out)
{
    const int tid = threadIdx.x;

    // ---------------- zero-streaming blocks ----------------
    if (blockIdx.x >= NBAND) {
        // float4 index i: bits [0:4)=x4, [4:10)=y, [10:16)=tx, [16:22)=ty, [22:24)=b
        float4* o4 = (float4*)out;
        const float4 z4 = make_float4(0.f, 0.f, 0.f, 0.f);
        const int total4 = 4 * 4096 * 64 * 16;            // 16,777,216
        const int stride = NZERO * BT;
        for (int i = (blockIdx.x - NBAND) * BT + tid; i < total4; i += stride) {
            int y  = (i >> 4) & 63;
            int ty = (i >> 16) & 63;
            int dy = y - ty;
            if (dy < -MD || dy > MD)
                o4[i] = z4;
        }
        return;
    }

    // ---------------- band-compute blocks ----------------
    const int bty = blockIdx.x;       // 0..255
    const int b   = bty >> 6;         // 0..3
    const int ty  = bty & 63;         // 0..63
    const int lane = tid & 63;        // u = x position
    const int w    = tid >> 6;        // 0..15
    const int cq   = w >> 2;          // channel quarter
    const int dyg  = w & 3;           // dy group

    // sVals[tx][dyi*9+dxi] = val(tx, y=ty+dyi-4, x=tx+dxi-4)
    __shared__ float sVals[64][81];   // 20.7 KB

    for (int i = tid; i < 64 * 81; i += BT)
        (&sVals[0][0])[i] = 0.0f;
    __syncthreads();

    const float* f1b = f1 + (size_t)(b * 256 + cq * 64) * 4096 + lane;
    const float* f2b = f2 + (size_t)(b * 256 + cq * 64) * 4096 + ty * 64 + lane;

    if      (dyg == 0) band_work<2>(f1b, f2b, ty, 0, lane, sVals);
    else if (dyg == 1) band_work<2>(f1b, f2b, ty, 2, lane, sVals);
    else if (dyg == 2) band_work<2>(f1b, f2b, ty, 4, lane, sVals);
    else               band_work<3>(f1b, f2b, ty, 6, lane, sVals);

    __syncthreads();

    // Band rows: full 64-float rows (9-wide value window, zeros elsewhere).
    float4* out4 = (float4*)(out + (size_t)(b * 4096 + ty * 64) * 4096);
    const int q4 = tid & 15;          // float4 index within a row
    const int ro = tid >> 4;          // row offset 0..63
    for (int rb = 0; rb < 64 * PATCH; rb += 64) {
        int row = rb + ro;            // row = tx*9 + dyi
        int tx  = row / PATCH;        // const divisor -> magic multiply
        int dyi = row - tx * PATCH;
        int y   = ty + dyi - MD;
        if ((unsigned)y < 64u) {
            float comp[4];
#pragma unroll
            for (int j = 0; j < 4; ++j) {
                int x  = q4 * 4 + j;
                int dx = x - tx;
                comp[j] = (dx >= -MD && dx <= MD) ? sVals[tx][dyi * PATCH + dx + MD] : 0.f;
            }
            out4[tx * 1024 + y * 16 + q4] = make_float4(comp[0], comp[1], comp[2], comp[3]);
        }
    }
}

extern "C" void kernel_launch(void* const* d_in, const int* in_sizes, int n_in,
                              void* d_out, int out_size, void* d_ws, size_t ws_size,
                              hipStream_t stream) {
    const float* f1 = (const float*)d_in[0];
    const float* f2 = (const float*)d_in[1];
    float* out = (float*)d_out;
    cv_kernel<<<NBAND + NZERO, BT, 0, stream>>>(f1, f2, out);
}